// Round 7
// baseline (34.657 us; speedup 1.0000x reference)
//
#include <hip/hip_runtime.h>
#include <math.h>

#define BB 32
#define SS 2048
#define DD 512
#define SBLOCKS 64   // blocks per batch in the scores kernel

typedef float f32x4 __attribute__((ext_vector_type(4)));

// ---------------------------------------------------------------------------
// K1: u[b,d] = sum_e hidden[b,e] * W[e,d], fully reduced.
// Bias dropped: adds a per-batch constant to every logit -> softmax-invariant.
// grid = (16, B) = 512 blocks (2/CU): block (dc,b) computes u[b, dc*32..+32).
// 256 threads = 16 e-groups x 16 float2 d-lanes; 32-iteration per-thread loop
// (was 64 at 256 blocks -- halves the serial load-latency batches).
// ---------------------------------------------------------------------------
__global__ void __launch_bounds__(256) compute_u_kernel(
    const float* __restrict__ hidden, const float* __restrict__ W,
    float* __restrict__ u) {
    const int dc = blockIdx.x;         // 0..15
    const int b  = blockIdx.y;
    const int t  = threadIdx.x;
    const int dp = t & 15;             // float2 lane within the 32-wide d-chunk
    const int eg = t >> 4;             // e-group: e in [eg*32, eg*32+32)

    __shared__ float h_s[DD];
    h_s[t]       = hidden[b * DD + t];
    h_s[t + 256] = hidden[b * DD + t + 256];
    __syncthreads();

    const float2* W2 = (const float2*)W;       // W2[e*(DD/2) + d/2]
    float2 acc = make_float2(0.f, 0.f);
    #pragma unroll 8
    for (int i = 0; i < 32; ++i) {
        const int e = eg * 32 + i;
        const float he = h_s[e];
        const float2 w = W2[(size_t)e * (DD / 2) + dc * 16 + dp];
        acc.x = fmaf(he, w.x, acc.x);
        acc.y = fmaf(he, w.y, acc.y);
    }

    __shared__ float2 red[16][16];
    red[eg][dp] = acc;
    __syncthreads();
    if (t < 16) {
        float2 s = make_float2(0.f, 0.f);
        #pragma unroll
        for (int g = 0; g < 16; ++g) {
            s.x += red[g][t].x;
            s.y += red[g][t].y;
        }
        ((float2*)(u + b * DD))[dc * 16 + t] = s;
    }
}

// ---------------------------------------------------------------------------
// K2: logits[b,s] = dot(enc[b,s,:], u[b,:]).
// grid = (SBLOCKS, B), block = 256 (4 waves). Lane l holds u[b,8l..8l+7].
// Contiguous tiling: wave w of block x owns rows [x*32+8w, +8), read as
// adjacent pairs (4 KB contiguous). enc loads are NON-TEMPORAL: the stream
// is single-use, nt bypasses L2 allocation (no pollution of the read path).
// Epilogue: per-block (max, sum-exp) partial -> 8 B. No cross-block sync
// (R3 lesson: 2048 agent-scope fences = 232us @ 3.7% BW).
// ---------------------------------------------------------------------------
__global__ void __launch_bounds__(256) scores_kernel(
    const float* __restrict__ enc, const float* __restrict__ u,
    float* __restrict__ logits, float2* __restrict__ partials) {
    const int b    = blockIdx.y;
    const int lane = threadIdx.x & 63;
    const int wv   = threadIdx.x >> 6;

    const f32x4* uv = (const f32x4*)(u + b * DD);
    const f32x4 u0 = uv[lane * 2 + 0];
    const f32x4 u1 = uv[lane * 2 + 1];

    const int rbase = blockIdx.x * 32 + wv * 8;   // this wave's 8 rows
    const f32x4* encb = (const f32x4*)(enc + (size_t)b * SS * DD);

    float rv[8];
    #pragma unroll
    for (int kk = 0; kk < 4; ++kk) {
        const int s0 = rbase + 2 * kk;            // adjacent pair: 4 KB contiguous
        const f32x4* r0 = encb + (size_t)s0 * (DD / 4);
        const f32x4* r1 = r0 + (DD / 4);
        const f32x4 a0 = __builtin_nontemporal_load(r0 + lane * 2 + 0);
        const f32x4 a1 = __builtin_nontemporal_load(r0 + lane * 2 + 1);
        const f32x4 c0 = __builtin_nontemporal_load(r1 + lane * 2 + 0);
        const f32x4 c1 = __builtin_nontemporal_load(r1 + lane * 2 + 1);
        float acc0 = a0[0] * u0[0] + a0[1] * u0[1] + a0[2] * u0[2] + a0[3] * u0[3]
                   + a1[0] * u1[0] + a1[1] * u1[1] + a1[2] * u1[2] + a1[3] * u1[3];
        float acc1 = c0[0] * u0[0] + c0[1] * u0[1] + c0[2] * u0[2] + c0[3] * u0[3]
                   + c1[0] * u1[0] + c1[1] * u1[1] + c1[2] * u1[2] + c1[3] * u1[3];
        #pragma unroll
        for (int off = 32; off > 0; off >>= 1) {
            acc0 += __shfl_xor(acc0, off, 64);
            acc1 += __shfl_xor(acc1, off, 64);
        }
        rv[2 * kk]     = acc0;                    // butterfly: all lanes hold sums
        rv[2 * kk + 1] = acc1;
        if (lane == 0)
            *(float2*)(logits + b * SS + s0) = make_float2(acc0, acc1);
    }

    // ---- per-block softmax partial: (max, sum exp) over its 32 rows --------
    float mw = rv[0];
    #pragma unroll
    for (int i = 1; i < 8; ++i) mw = fmaxf(mw, rv[i]);
    float sw = 0.f;
    #pragma unroll
    for (int i = 0; i < 8; ++i) sw += __expf(rv[i] - mw);

    __shared__ float2 wred[4];
    if (lane == 0) wred[wv] = make_float2(mw, sw);
    __syncthreads();
    if (threadIdx.x == 0) {
        float2 p0 = wred[0], p1 = wred[1], p2 = wred[2], p3 = wred[3];
        float mb = fmaxf(fmaxf(p0.x, p1.x), fmaxf(p2.x, p3.x));
        float sb = p0.y * __expf(p0.x - mb) + p1.y * __expf(p1.x - mb)
                 + p2.y * __expf(p2.x - mb) + p3.y * __expf(p3.x - mb);
        partials[b * SBLOCKS + blockIdx.x] = make_float2(mb, sb);
    }
}

// ---------------------------------------------------------------------------
// K3: normalize. grid = (2, B), block = 256; thread handles one float4.
// Every wave redundantly reduces the 64 (m,S) partials via shuffles (512 B,
// no LDS, no syncthreads), then applies exp(x-m)/S elementwise in place.
// ---------------------------------------------------------------------------
__global__ void __launch_bounds__(256) normalize_kernel(
    float* __restrict__ logits, const float2* __restrict__ partials) {
    const int b    = blockIdx.y;
    const int lane = threadIdx.x & 63;

    const float2 pl = partials[b * SBLOCKS + lane];
    float m = pl.x;
    #pragma unroll
    for (int off = 32; off > 0; off >>= 1)
        m = fmaxf(m, __shfl_xor(m, off, 64));
    float s = pl.y * __expf(pl.x - m);
    #pragma unroll
    for (int off = 32; off > 0; off >>= 1)
        s += __shfl_xor(s, off, 64);
    const float inv = 1.f / s;

    float4* p = (float4*)(logits + b * SS);
    const int idx = blockIdx.x * 256 + threadIdx.x;     // 512 float4s per batch
    float4 v = p[idx];
    v.x = __expf(v.x - m) * inv;
    v.y = __expf(v.y - m) * inv;
    v.z = __expf(v.z - m) * inv;
    v.w = __expf(v.w - m) * inv;
    p[idx] = v;
}

extern "C" void kernel_launch(void* const* d_in, const int* in_sizes, int n_in,
                              void* d_out, int out_size, void* d_ws, size_t ws_size,
                              hipStream_t stream) {
    const float* hidden = (const float*)d_in[0];   // [B,1,D]
    const float* enc    = (const float*)d_in[1];   // [B,S,D]
    const float* W      = (const float*)d_in[2];   // [D,D] (W[e,d])
    // d_in[3] = bias: per-batch constant on all logits -> softmax-invariant, unused.
    float* out  = (float*)d_out;                   // [B,1,S] fp32
    float* u    = (float*)d_ws;                    // B*D floats = 64 KB
    float2* partials = (float2*)((char*)d_ws + (size_t)BB * DD * sizeof(float));

    compute_u_kernel<<<dim3(16, BB), dim3(256), 0, stream>>>(hidden, W, u);
    scores_kernel<<<dim3(SBLOCKS, BB), dim3(256), 0, stream>>>(enc, u, out, partials);
    normalize_kernel<<<dim3(2, BB), dim3(256), 0, stream>>>(out, partials);
}

// Round 8
// 31.767 us; speedup vs baseline: 1.0910x; 1.0910x over previous
//
#include <hip/hip_runtime.h>
#include <math.h>

#define BB 32
#define SS 2048
#define DD 512
#define SBLOCKS 64   // blocks per batch in the scores kernel

typedef float f32x4 __attribute__((ext_vector_type(4)));

// ---------------------------------------------------------------------------
// K1: u[b,d] = sum_e hidden[b,e] * W[e,d], fully reduced.
// Bias dropped: adds a per-batch constant to every logit -> softmax-invariant.
// grid = (16, B) = 512 blocks (2/CU): block (dc,b) computes u[b, dc*32..+32).
// 256 threads = 16 e-groups x 16 float2 d-lanes; 32-iteration per-thread loop.
// ---------------------------------------------------------------------------
__global__ void __launch_bounds__(256) compute_u_kernel(
    const float* __restrict__ hidden, const float* __restrict__ W,
    float* __restrict__ u) {
    const int dc = blockIdx.x;         // 0..15
    const int b  = blockIdx.y;
    const int t  = threadIdx.x;
    const int dp = t & 15;             // float2 lane within the 32-wide d-chunk
    const int eg = t >> 4;             // e-group: e in [eg*32, eg*32+32)

    __shared__ float h_s[DD];
    h_s[t]       = hidden[b * DD + t];
    h_s[t + 256] = hidden[b * DD + t + 256];
    __syncthreads();

    const float2* W2 = (const float2*)W;       // W2[e*(DD/2) + d/2]
    float2 acc = make_float2(0.f, 0.f);
    #pragma unroll 8
    for (int i = 0; i < 32; ++i) {
        const int e = eg * 32 + i;
        const float he = h_s[e];
        const float2 w = W2[(size_t)e * (DD / 2) + dc * 16 + dp];
        acc.x = fmaf(he, w.x, acc.x);
        acc.y = fmaf(he, w.y, acc.y);
    }

    __shared__ float2 red[16][16];
    red[eg][dp] = acc;
    __syncthreads();
    if (t < 16) {
        float2 s = make_float2(0.f, 0.f);
        #pragma unroll
        for (int g = 0; g < 16; ++g) {
            s.x += red[g][t].x;
            s.y += red[g][t].y;
        }
        ((float2*)(u + b * DD))[dc * 16 + t] = s;
    }
}

// ---------------------------------------------------------------------------
// K2: logits[b,s] = dot(enc[b,s,:], u[b,:]).
// grid = (SBLOCKS, B), block = 256 (4 waves). Lane l holds u[b,8l..8l+7].
// Contiguous tiling: wave w of block x owns rows [x*32+8w, +8), read as
// adjacent pairs (4 KB contiguous). PLAIN cached loads: enc is ~half
// L3-resident across graph replays (R3 profile: FETCH 67MB of 134MB) --
// R7's nontemporal loads forfeited that reuse and regressed 2us.
// Epilogue: per-block (max, sum-exp) partial -> 8 B. No cross-block sync
// (R3 lesson: 2048 agent-scope fences = 232us @ 3.7% BW).
// ---------------------------------------------------------------------------
__global__ void __launch_bounds__(256) scores_kernel(
    const float* __restrict__ enc, const float* __restrict__ u,
    float* __restrict__ logits, float2* __restrict__ partials) {
    const int b    = blockIdx.y;
    const int lane = threadIdx.x & 63;
    const int wv   = threadIdx.x >> 6;

    const f32x4* uv = (const f32x4*)(u + b * DD);
    const f32x4 u0 = uv[lane * 2 + 0];
    const f32x4 u1 = uv[lane * 2 + 1];

    const int rbase = blockIdx.x * 32 + wv * 8;   // this wave's 8 rows
    const f32x4* encb = (const f32x4*)(enc + (size_t)b * SS * DD);

    float rv[8];
    #pragma unroll
    for (int kk = 0; kk < 4; ++kk) {
        const int s0 = rbase + 2 * kk;            // adjacent pair: 4 KB contiguous
        const f32x4* r0 = encb + (size_t)s0 * (DD / 4);
        const f32x4* r1 = r0 + (DD / 4);
        const f32x4 a0 = r0[lane * 2 + 0];
        const f32x4 a1 = r0[lane * 2 + 1];
        const f32x4 c0 = r1[lane * 2 + 0];
        const f32x4 c1 = r1[lane * 2 + 1];
        float acc0 = a0[0] * u0[0] + a0[1] * u0[1] + a0[2] * u0[2] + a0[3] * u0[3]
                   + a1[0] * u1[0] + a1[1] * u1[1] + a1[2] * u1[2] + a1[3] * u1[3];
        float acc1 = c0[0] * u0[0] + c0[1] * u0[1] + c0[2] * u0[2] + c0[3] * u0[3]
                   + c1[0] * u1[0] + c1[1] * u1[1] + c1[2] * u1[2] + c1[3] * u1[3];
        #pragma unroll
        for (int off = 32; off > 0; off >>= 1) {
            acc0 += __shfl_xor(acc0, off, 64);
            acc1 += __shfl_xor(acc1, off, 64);
        }
        rv[2 * kk]     = acc0;                    // butterfly: all lanes hold sums
        rv[2 * kk + 1] = acc1;
        if (lane == 0)
            *(float2*)(logits + b * SS + s0) = make_float2(acc0, acc1);
    }

    // ---- per-block softmax partial: (max, sum exp) over its 32 rows --------
    float mw = rv[0];
    #pragma unroll
    for (int i = 1; i < 8; ++i) mw = fmaxf(mw, rv[i]);
    float sw = 0.f;
    #pragma unroll
    for (int i = 0; i < 8; ++i) sw += __expf(rv[i] - mw);

    __shared__ float2 wred[4];
    if (lane == 0) wred[wv] = make_float2(mw, sw);
    __syncthreads();
    if (threadIdx.x == 0) {
        float2 p0 = wred[0], p1 = wred[1], p2 = wred[2], p3 = wred[3];
        float mb = fmaxf(fmaxf(p0.x, p1.x), fmaxf(p2.x, p3.x));
        float sb = p0.y * __expf(p0.x - mb) + p1.y * __expf(p1.x - mb)
                 + p2.y * __expf(p2.x - mb) + p3.y * __expf(p3.x - mb);
        partials[b * SBLOCKS + blockIdx.x] = make_float2(mb, sb);
    }
}

// ---------------------------------------------------------------------------
// K3: normalize. grid = (2, B), block = 256; thread handles one float4.
// Every wave redundantly reduces the 64 (m,S) partials via shuffles (512 B,
// no LDS, no syncthreads), then applies exp(x-m)/S elementwise in place.
// ---------------------------------------------------------------------------
__global__ void __launch_bounds__(256) normalize_kernel(
    float* __restrict__ logits, const float2* __restrict__ partials) {
    const int b    = blockIdx.y;
    const int lane = threadIdx.x & 63;

    const float2 pl = partials[b * SBLOCKS + lane];
    float m = pl.x;
    #pragma unroll
    for (int off = 32; off > 0; off >>= 1)
        m = fmaxf(m, __shfl_xor(m, off, 64));
    float s = pl.y * __expf(pl.x - m);
    #pragma unroll
    for (int off = 32; off > 0; off >>= 1)
        s += __shfl_xor(s, off, 64);
    const float inv = 1.f / s;

    float4* p = (float4*)(logits + b * SS);
    const int idx = blockIdx.x * 256 + threadIdx.x;     // 512 float4s per batch
    float4 v = p[idx];
    v.x = __expf(v.x - m) * inv;
    v.y = __expf(v.y - m) * inv;
    v.z = __expf(v.z - m) * inv;
    v.w = __expf(v.w - m) * inv;
    p[idx] = v;
}

extern "C" void kernel_launch(void* const* d_in, const int* in_sizes, int n_in,
                              void* d_out, int out_size, void* d_ws, size_t ws_size,
                              hipStream_t stream) {
    const float* hidden = (const float*)d_in[0];   // [B,1,D]
    const float* enc    = (const float*)d_in[1];   // [B,S,D]
    const float* W      = (const float*)d_in[2];   // [D,D] (W[e,d])
    // d_in[3] = bias: per-batch constant on all logits -> softmax-invariant, unused.
    float* out  = (float*)d_out;                   // [B,1,S] fp32
    float* u    = (float*)d_ws;                    // B*D floats = 64 KB
    float2* partials = (float2*)((char*)d_ws + (size_t)BB * DD * sizeof(float));

    compute_u_kernel<<<dim3(16, BB), dim3(256), 0, stream>>>(hidden, W, u);
    scores_kernel<<<dim3(SBLOCKS, BB), dim3(256), 0, stream>>>(enc, u, out, partials);
    normalize_kernel<<<dim3(2, BB), dim3(256), 0, stream>>>(out, partials);
}